// Round 14
// baseline (52.640 us; speedup 1.0000x reference)
//
#include <hip/hip_runtime.h>
#include <hip/hip_bf16.h>

#define B_ 2
#define N_ 4096
#define C_ 32
#define O_ 32
#define NCELLS 27
#define FDIM (NCELLS * C_)   // 864
#define CAP 256
#define G_ 5
#define NBIN 125             // per batch

typedef __attribute__((ext_vector_type(16))) float f32x16;
typedef __attribute__((ext_vector_type(4)))  float f32x4;
typedef __attribute__((ext_vector_type(8)))  short bf16x8;

constexpr float SIGMA = 2546.4790894703255f;   // 8/(pi*h^3), h=0.1
constexpr float SIG6  = 6.0f * SIGMA;
constexpr float SIG2  = 2.0f * SIGMA;
constexpr float RC2TH = 0.010001f;             // (rounded-cube dist)^2 < r^2, tiny margin

__device__ __forceinline__ unsigned short bf16_rne(float f) {
    unsigned u = __float_as_uint(f);
    u += 0x7fffu + ((u >> 16) & 1u);
    return (unsigned short)(u >> 16);
}
__device__ __forceinline__ int bin1(float x) {
    int v = (int)(x * 5.0f);
    return v < 0 ? 0 : (v > 4 ? 4 : v);
}

// ---- K0: zero bin counters (kernel, not hipMemsetAsync -> no fill node in our graph) ----
__global__ void __launch_bounds__(256) zero_kernel(int* __restrict__ cnt) {
    cnt[threadIdx.x] = 0;
    cnt[256 + threadIdx.x] = 0;
}

// ---- K1: coefh bf16 (8 channels/thread); W2 hi plane in B-frag order; bin histogram ----
__global__ void __launch_bounds__(256) prep_kernel(const float* __restrict__ locs,
                                                   const float* __restrict__ data,
                                                   const float* __restrict__ density,
                                                   const float* __restrict__ weight,
                                                   unsigned short* __restrict__ coefh,
                                                   unsigned short* __restrict__ W2fh,
                                                   int* __restrict__ cnt) {
    int t = blockIdx.x * 256 + threadIdx.x;
    if (t < 32768) {                              // coef: row bj, channels c0..c0+7
        int bj = t >> 2;
        int c0 = (t & 3) * 8;
        float im = locs[bj * 4 + 3];
        float de = density[bj];
        float sc = 1.0f / (im * de);
        const float4* dr = reinterpret_cast<const float4*>(data + bj * 32 + c0);
        float4 a = dr[0], b2 = dr[1];
        unsigned r0 = (unsigned)bf16_rne(a.x * sc) | ((unsigned)bf16_rne(a.y * sc) << 16);
        unsigned r1 = (unsigned)bf16_rne(a.z * sc) | ((unsigned)bf16_rne(a.w * sc) << 16);
        unsigned r2 = (unsigned)bf16_rne(b2.x * sc) | ((unsigned)bf16_rne(b2.y * sc) << 16);
        unsigned r3 = (unsigned)bf16_rne(b2.z * sc) | ((unsigned)bf16_rne(b2.w * sc) << 16);
        uint4 outv = make_uint4(r0, r1, r2, r3);
        *reinterpret_cast<uint4*>(coefh + bj * 32 + c0) = outv;
    } else if (t < 60416) {                       // W2: 2 ntiles * 27 kc * 64 lanes * 8 regs
        int u = t - 32768;
        int b    = u & 7;
        int l    = (u >> 3) & 63;
        int rest = u >> 9;
        int kc   = rest % 27;
        int nt   = rest / 27;
        int f    = kc * 32 + ((l >> 4) & 3) * 8 + b;
        int m    = f >> 5;
        int n    = f & 31;
        int o    = nt * 16 + (l & 15);
        W2fh[u] = bf16_rne(weight[(o * C_ + n) * NCELLS + m]);
    } else {                                      // 0..8191: bin histogram
        int v = t - 60416;
        const float4* pos4 = reinterpret_cast<const float4*>(locs);
        float4 p = pos4[v];
        int bidx = (v >> 12) * NBIN + (bin1(p.x) * G_ + bin1(p.y)) * G_ + bin1(p.z);
        atomicAdd(&cnt[bidx], 1);
    }
}

// ---- K1c: per-block prefix (wave 0) + scatter into bin-sorted order; off also to global ----
__global__ void __launch_bounds__(256) scatter_kernel(const float* __restrict__ locs,
                                                      const int* __restrict__ cnt,
                                                      int* __restrict__ wcnt,
                                                      int* __restrict__ off_g,
                                                      float4* __restrict__ spos) {
    __shared__ int soff[256];
    if (threadIdx.x < 64) {
        int l = threadIdx.x;
        int c0 = cnt[4 * l + 0], c1 = cnt[4 * l + 1], c2 = cnt[4 * l + 2], c3 = cnt[4 * l + 3];
        int s01 = c0 + c1;
        int s = s01 + c2 + c3;
        int incl = s;
#pragma unroll
        for (int d = 1; d < 64; d <<= 1) {
            int tt = __shfl_up(incl, d);
            if (l >= d) incl += tt;
        }
        int excl = incl - s;
        soff[4 * l + 0] = excl;
        soff[4 * l + 1] = excl + c0;
        soff[4 * l + 2] = excl + s01;
        soff[4 * l + 3] = excl + s01 + c2;
        off_g[4 * l + 0] = excl;                  // all blocks write identical values
        off_g[4 * l + 1] = excl + c0;
        off_g[4 * l + 2] = excl + s01;
        off_g[4 * l + 3] = excl + s01 + c2;
    }
    __syncthreads();
    int v = blockIdx.x * 256 + threadIdx.x;       // 0..8191
    const float4* pos4 = reinterpret_cast<const float4*>(locs);
    float4 p = pos4[v];
    int bidx = (v >> 12) * NBIN + (bin1(p.x) * G_ + bin1(p.y)) * G_ + bin1(p.z);
    int r = atomicAdd(&wcnt[bidx], 1);
    int dst = soff[bidx] + r;
    if (dst >= 0 && dst < B_ * N_)
        spos[dst] = make_float4(p.x, p.y, p.z, __int_as_float((v & (N_ - 1)) << 6));
}

// ---- K2: one wave per sorted query; 128-particle scan; sentinel-padded LDS queue;
//          flush with cross-batch coef-gather pipeline (T14 async split); MFMA 32x32x16 ----
__global__ void __launch_bounds__(64) field_kernel(const float4* __restrict__ spos,
                                                   const int* __restrict__ off,
                                                   const unsigned short* __restrict__ coefh,
                                                   unsigned short* __restrict__ fieldh) {
    __shared__ float4 candbuf[CAP];               // 4 KB

    const int lane = threadIdx.x;
    const int qi   = blockIdx.x;                  // SORTED slot
    const int bi   = qi >> 12;                    // batch (bins are batch-major)

    float4 pq = spos[qi];
    const float xi = pq.x, yi = pq.y, zi = pq.z;

    // lane owns cell m32 = lane&31; dead lanes (>=27) pushed far away -> w==0
    const int m32 = lane & 31;
    const int h   = lane >> 5;
    const float ox = (m32 < NCELLS) ? 0.05f * (float)((m32 / 9) - 1)       : 1e4f;
    const float oy = (m32 < NCELLS) ? 0.05f * (float)(((m32 / 3) % 3) - 1) : 1e4f;
    const float oz = (m32 < NCELLS) ? 0.05f * (float)((m32 % 3) - 1)       : 1e4f;

    const char* cb = (const char*)(coefh + (size_t)bi * N_ * C_ + m32);   // + j<<6 bytes

    f32x16 acc;
#pragma unroll
    for (int r = 0; r < 16; ++r) acc[r] = 0.0f;

    const unsigned long long lanemask = (1ull << lane) - 1ull;
    int count = 0;
    float4* myq = candbuf;

    auto flush = [&](int cnt_) {
        if (cnt_ <= 0) return;
        // pad queue to a multiple of 16 with far-away sentinels (w -> 0, j -> 0)
        int pad = (16 - (cnt_ & 15)) & 15;
        if (lane < pad) myq[cnt_ + lane] = make_float4(1e4f, 1e4f, 1e4f, __int_as_float(0));
        asm volatile("s_waitcnt lgkmcnt(0)" ::: "memory");
        int nb = (cnt_ + 15) >> 4;
        const float* qw = (const float*)myq;      // .w at word index slot*4+3
        unsigned cfN[8], cfC[8];
        // prefetch batch 0's coef gathers (addresses via cheap broadcast b32 reads)
#pragma unroll
        for (int b = 0; b < 8; ++b)
            cfN[b] = *(const unsigned short*)(cb + __float_as_int(qw[(h * 8 + b) * 4 + 3]));
        for (int bt = 0; bt < nb; ++bt) {
#pragma unroll
            for (int b = 0; b < 8; ++b) cfC[b] = cfN[b];   // waits on in-flight loads
            if (bt + 1 < nb) {                             // issue NEXT batch's gathers now;
                int nbase = (bt + 1) * 16 + h * 8;         // they fly under this batch's VALU
#pragma unroll
                for (int b = 0; b < 8; ++b)
                    cfN[b] = *(const unsigned short*)(cb +
                              __float_as_int(qw[(nbase + b) * 4 + 3]));
            }
            int base = bt * 16 + h * 8;
            float wv[8];
#pragma unroll
            for (int b = 0; b < 8; ++b) {
                float4 cd = myq[base + b];        // uniform addr per half-wave -> broadcast
                float tx = cd.x + ox;
                float ty = cd.y + oy;
                float tz = cd.z + oz;
                float d2 = fmaf(tz, tz, fmaf(ty, ty, tx * tx));   // >= 0 always
                float q2 = d2 * 100.0f;
                float q  = __builtin_amdgcn_sqrtf(q2);
                float w1 = fmaf(q2, fmaf(SIG6, q, -SIG6), SIGMA); // sigma*(1-6q^2+6q^3)
                float u1 = 1.0f - q;
                float w2 = (SIG2 * u1) * (u1 * u1);               // <=0 for q>=1
                // w1-w2 = sigma*(2q-1)^3  =>  exact spline = max(min(w1,w2),0)
                wv[b] = fmaxf(fminf(w1, w2), 0.0f);
            }
            union { bf16x8 v; unsigned u[4]; } aF, bF;
#pragma unroll
            for (int wg = 0; wg < 4; ++wg) {
                unsigned pk;
                asm("v_cvt_pk_bf16_f32 %0, %1, %2" : "=v"(pk)
                    : "v"(wv[2 * wg]), "v"(wv[2 * wg + 1]));
                aF.u[wg] = pk;
                bF.u[wg] = cfC[2 * wg] | (cfC[2 * wg + 1] << 16);
            }
            acc = __builtin_amdgcn_mfma_f32_32x32x16_bf16(aF.v, bF.v, acc, 0, 0, 0);
        }
    };

    // 9 z-runs of the 3x3x3 bin neighborhood; bounds fetched by lanes 0..8
    const int qbx = bin1(xi), qby = bin1(yi), qbz = bin1(zi);
    const int zlo = qbz > 0 ? qbz - 1 : 0;
    const int zhi = qbz < 4 ? qbz + 1 : 4;
    int rdx = lane / 3;
    int rdy = lane - rdx * 3;
    int bx = qbx + rdx - 1;
    int by = qby + rdy - 1;
    bool vv = (lane < 9) && (bx >= 0) && (bx < G_) && (by >= 0) && (by < G_);
    int bb = bi * NBIN + (bx * G_ + by) * G_;
    int vs0 = off[vv ? bb + zlo : 0];
    int vs1 = off[vv ? bb + zhi + 1 : 0];
    // defensive clamp: guarantee bounded loops even under corrupted workspace
    vs0 = vv ? (vs0 < 0 ? 0 : (vs0 > B_ * N_ ? B_ * N_ : vs0)) : 0;
    vs1 = vv ? (vs1 < vs0 ? vs0 : (vs1 > B_ * N_ ? B_ * N_ : vs1)) : 0;

    for (int r = 0; r < 9; ++r) {
        int rs = __shfl(vs0, r);
        int re = __shfl(vs1, r);
        for (int s = rs; s < re; s += 128) {
            int idx0 = s + lane;
            int idx1 = s + 64 + lane;
            bool val0 = idx0 < re;
            bool val1 = idx1 < re;
            float4 pj0 = spos[val0 ? idx0 : rs];   // two independent loads -> MLP 2
            float4 pj1 = spos[val1 ? idx1 : rs];
            // chunk 0 filter
            float dx0 = xi - pj0.x, dy0 = yi - pj0.y, dz0 = zi - pj0.z;
            float ax0 = fmaxf(fabsf(dx0) - 0.05f, 0.0f);
            float ay0 = fmaxf(fabsf(dy0) - 0.05f, 0.0f);
            float az0 = fmaxf(fabsf(dz0) - 0.05f, 0.0f);
            float rc0 = fmaf(az0, az0, fmaf(ay0, ay0, ax0 * ax0));
            bool hit0 = val0 && (rc0 < RC2TH);
            // chunk 1 filter
            float dx1 = xi - pj1.x, dy1 = yi - pj1.y, dz1 = zi - pj1.z;
            float ax1 = fmaxf(fabsf(dx1) - 0.05f, 0.0f);
            float ay1 = fmaxf(fabsf(dy1) - 0.05f, 0.0f);
            float az1 = fmaxf(fabsf(dz1) - 0.05f, 0.0f);
            float rc1 = fmaf(az1, az1, fmaf(ay1, ay1, ax1 * ax1));
            bool hit1 = val1 && (rc1 < RC2TH);
            // compact chunk 0 then chunk 1
            unsigned long long m0 = __ballot(hit0);
            if (hit0) {
                int pos = count + __popcll(m0 & lanemask);
                myq[pos] = make_float4(dx0, dy0, dz0, pj0.w);
            }
            count += __popcll(m0);
            unsigned long long m1 = __ballot(hit1);
            if (hit1) {
                int pos = count + __popcll(m1 & lanemask);
                myq[pos] = make_float4(dx1, dy1, dz1, pj1.w);
            }
            count += __popcll(m1);
            if (count > CAP - 128) { flush(count); count = 0; }
        }
    }
    flush(count);

    // epilogue: f32 acc -> single bf16 plane (row = sorted slot qi)
    // C/D: row m=(r&3)+8*(r>>2)+4*h, col=lane&31
    unsigned short* fh = fieldh + (size_t)qi * FDIM + m32;
#pragma unroll
    for (int r = 0; r < 16; ++r) {
        int m = (r & 3) + 8 * (r >> 2) + 4 * h;
        if (m < NCELLS) fh[m * 32] = bf16_rne(acc[r]);
    }
}

// ---- K3: out = bias + FIELD(8192x864,sorted) . W2(864x32); un-permute rows on store ----
__global__ void __launch_bounds__(64) out_kernel(const unsigned short* __restrict__ fieldh,
                                                 const unsigned short* __restrict__ W2fh,
                                                 const float4* __restrict__ spos,
                                                 const float* __restrict__ bias,
                                                 float* __restrict__ out) {
    const int lane = threadIdx.x;
    const int row0 = blockIdx.x * 16;             // sorted-row tile
    const int arow = row0 + (lane & 15);          // A row (sorted query slot)
    const int kg   = lane >> 4;

    const bf16x8* Bh = reinterpret_cast<const bf16x8*>(W2fh);
    const unsigned short* fh = fieldh + (size_t)arow * FDIM;

    f32x4 acc0, acc1;
#pragma unroll
    for (int r = 0; r < 4; ++r) { acc0[r] = 0.0f; acc1[r] = 0.0f; }

    for (int kc = 0; kc < 27; ++kc) {
        int k0 = kc * 32 + kg * 8;
        bf16x8 ah  = *reinterpret_cast<const bf16x8*>(fh + k0);
        bf16x8 bh0 = Bh[kc * 64 + lane];
        bf16x8 bh1 = Bh[(27 + kc) * 64 + lane];
        acc0 = __builtin_amdgcn_mfma_f32_16x16x32_bf16(ah, bh0, acc0, 0, 0, 0);
        acc1 = __builtin_amdgcn_mfma_f32_16x16x32_bf16(ah, bh1, acc1, 0, 0, 0);
    }

    int col = lane & 15;
    float b0 = bias[col];
    float b1 = bias[16 + col];
#pragma unroll
    for (int r = 0; r < 4; ++r) {
        int srow = row0 + kg * 4 + r;             // sorted slot of this output row
        int oj   = __float_as_int(spos[srow].w) >> 6;          // original index in batch
        int orow = (srow >= N_ ? N_ : 0) + oj;                  // + batch offset
        out[(size_t)orow * O_ + col]      = acc0[r] + b0;
        out[(size_t)orow * O_ + 16 + col] = acc1[r] + b1;
    }
}

extern "C" void kernel_launch(void* const* d_in, const int* in_sizes, int n_in,
                              void* d_out, int out_size, void* d_ws, size_t ws_size,
                              hipStream_t stream) {
    const float* locs    = (const float*)d_in[0];
    const float* data    = (const float*)d_in[1];
    const float* density = (const float*)d_in[2];
    const float* weight  = (const float*)d_in[3];
    const float* bias    = (const float*)d_in[4];
    float* out = (float*)d_out;

    char* base = (char*)d_ws;
    float4* spos           = (float4*)base;                                 // 8192*16B
    unsigned short* fieldh = (unsigned short*)(base + 131072);              // 8192*864 u16
    unsigned short* coefh  = fieldh + (size_t)B_ * N_ * FDIM;               // 262144 u16
    unsigned short* W2fh   = coefh + (size_t)B_ * N_ * C_;                  // 27648 u16
    int* cnt  = (int*)(W2fh + 27648);                                       // 256 ints
    int* wcnt = cnt + 256;                                                  // 256 ints
    int* off  = wcnt + 256;                                                 // 256 ints

    zero_kernel<<<dim3(1), dim3(256), 0, stream>>>(cnt);                    // cnt + wcnt

    // K1: coef 32768 + W2 27648 + histogram 8192 = 68608 = 268*256
    prep_kernel<<<dim3(268), dim3(256), 0, stream>>>(locs, data, density, weight,
                                                     coefh, W2fh, cnt);

    scatter_kernel<<<dim3(32), dim3(256), 0, stream>>>(locs, cnt, wcnt, off, spos);

    // K2: one single-wave block per sorted query
    field_kernel<<<dim3(B_ * N_), dim3(64), 0, stream>>>(spos, off, coefh, fieldh);

    out_kernel<<<dim3((B_ * N_) / 16), dim3(64), 0, stream>>>(fieldh, W2fh, spos,
                                                              bias, out);
}

// Round 16
// 50.630 us; speedup vs baseline: 1.0397x; 1.0397x over previous
//
#include <hip/hip_runtime.h>
#include <hip/hip_bf16.h>

#define B_ 2
#define N_ 4096
#define C_ 32
#define O_ 32
#define NCELLS 27
#define FDIM (NCELLS * C_)   // 864
#define CAP 256
#define G_ 5
#define NBIN 125             // per batch

typedef __attribute__((ext_vector_type(16))) float f32x16;
typedef __attribute__((ext_vector_type(4)))  float f32x4;
typedef __attribute__((ext_vector_type(8)))  short bf16x8;

constexpr float SIGMA = 2546.4790894703255f;   // 8/(pi*h^3), h=0.1
constexpr float SIG6  = 6.0f * SIGMA;
constexpr float SIG2  = 2.0f * SIGMA;
constexpr float RC2TH = 0.010001f;             // (rounded-cube dist)^2 < r^2, tiny margin

__device__ __forceinline__ unsigned short bf16_rne(float f) {
    unsigned u = __float_as_uint(f);
    u += 0x7fffu + ((u >> 16) & 1u);
    return (unsigned short)(u >> 16);
}
__device__ __forceinline__ int bin1(float x) {
    int v = (int)(x * 5.0f);
    return v < 0 ? 0 : (v > 4 ? 4 : v);
}

// ---- K0: zero bin counters (kernel, not hipMemsetAsync -> no fill node in our graph) ----
__global__ void __launch_bounds__(256) zero_kernel(int* __restrict__ cnt) {
    cnt[threadIdx.x] = 0;
    cnt[256 + threadIdx.x] = 0;
}

// ---- K1: coefh bf16 (8 channels/thread); W2 hi plane in B-frag order; bin histogram ----
__global__ void __launch_bounds__(256) prep_kernel(const float* __restrict__ locs,
                                                   const float* __restrict__ data,
                                                   const float* __restrict__ density,
                                                   const float* __restrict__ weight,
                                                   unsigned short* __restrict__ coefh,
                                                   unsigned short* __restrict__ W2fh,
                                                   int* __restrict__ cnt) {
    int t = blockIdx.x * 256 + threadIdx.x;
    if (t < 32768) {                              // coef: row bj, channels c0..c0+7
        int bj = t >> 2;
        int c0 = (t & 3) * 8;
        float im = locs[bj * 4 + 3];
        float de = density[bj];
        float sc = 1.0f / (im * de);
        const float4* dr = reinterpret_cast<const float4*>(data + bj * 32 + c0);
        float4 a = dr[0], b2 = dr[1];
        unsigned r0 = (unsigned)bf16_rne(a.x * sc) | ((unsigned)bf16_rne(a.y * sc) << 16);
        unsigned r1 = (unsigned)bf16_rne(a.z * sc) | ((unsigned)bf16_rne(a.w * sc) << 16);
        unsigned r2 = (unsigned)bf16_rne(b2.x * sc) | ((unsigned)bf16_rne(b2.y * sc) << 16);
        unsigned r3 = (unsigned)bf16_rne(b2.z * sc) | ((unsigned)bf16_rne(b2.w * sc) << 16);
        uint4 outv = make_uint4(r0, r1, r2, r3);
        *reinterpret_cast<uint4*>(coefh + bj * 32 + c0) = outv;
    } else if (t < 60416) {                       // W2: 2 ntiles * 27 kc * 64 lanes * 8 regs
        int u = t - 32768;
        int b    = u & 7;
        int l    = (u >> 3) & 63;
        int rest = u >> 9;
        int kc   = rest % 27;
        int nt   = rest / 27;
        int f    = kc * 32 + ((l >> 4) & 3) * 8 + b;
        int m    = f >> 5;
        int n    = f & 31;
        int o    = nt * 16 + (l & 15);
        W2fh[u] = bf16_rne(weight[(o * C_ + n) * NCELLS + m]);
    } else {                                      // 0..8191: bin histogram
        int v = t - 60416;
        const float4* pos4 = reinterpret_cast<const float4*>(locs);
        float4 p = pos4[v];
        int bidx = (v >> 12) * NBIN + (bin1(p.x) * G_ + bin1(p.y)) * G_ + bin1(p.z);
        atomicAdd(&cnt[bidx], 1);
    }
}

// ---- K1c: per-block prefix (wave 0) + scatter into bin-sorted order; off also to global ----
__global__ void __launch_bounds__(256) scatter_kernel(const float* __restrict__ locs,
                                                      const int* __restrict__ cnt,
                                                      int* __restrict__ wcnt,
                                                      int* __restrict__ off_g,
                                                      float4* __restrict__ spos) {
    __shared__ int soff[256];
    if (threadIdx.x < 64) {
        int l = threadIdx.x;
        int c0 = cnt[4 * l + 0], c1 = cnt[4 * l + 1], c2 = cnt[4 * l + 2], c3 = cnt[4 * l + 3];
        int s01 = c0 + c1;
        int s = s01 + c2 + c3;
        int incl = s;
#pragma unroll
        for (int d = 1; d < 64; d <<= 1) {
            int tt = __shfl_up(incl, d);
            if (l >= d) incl += tt;
        }
        int excl = incl - s;
        soff[4 * l + 0] = excl;
        soff[4 * l + 1] = excl + c0;
        soff[4 * l + 2] = excl + s01;
        soff[4 * l + 3] = excl + s01 + c2;
        off_g[4 * l + 0] = excl;                  // all blocks write identical values
        off_g[4 * l + 1] = excl + c0;
        off_g[4 * l + 2] = excl + s01;
        off_g[4 * l + 3] = excl + s01 + c2;
    }
    __syncthreads();
    int v = blockIdx.x * 256 + threadIdx.x;       // 0..8191
    const float4* pos4 = reinterpret_cast<const float4*>(locs);
    float4 p = pos4[v];
    int bidx = (v >> 12) * NBIN + (bin1(p.x) * G_ + bin1(p.y)) * G_ + bin1(p.z);
    int r = atomicAdd(&wcnt[bidx], 1);
    int dst = soff[bidx] + r;
    if (dst >= 0 && dst < B_ * N_)
        spos[dst] = make_float4(p.x, p.y, p.z, __int_as_float((v & (N_ - 1)) << 6));
}

// ---- K2: one wave per sorted query; z-clipped + column-pruned scan (conservative-exact);
//          128-particle scan iterations; sentinel-padded LDS queue; MFMA 32x32x16 ----
__global__ void __launch_bounds__(64) field_kernel(const float4* __restrict__ spos,
                                                   const int* __restrict__ off,
                                                   const unsigned short* __restrict__ coefh,
                                                   unsigned short* __restrict__ fieldh) {
    __shared__ float4 candbuf[CAP];               // 4 KB

    const int lane = threadIdx.x;
    const int qi   = blockIdx.x;                  // SORTED slot
    const int bi   = qi >> 12;                    // batch (bins are batch-major)

    float4 pq = spos[qi];
    const float xi = pq.x, yi = pq.y, zi = pq.z;

    // lane owns cell m32 = lane&31; dead lanes (>=27) pushed far away -> w==0
    const int m32 = lane & 31;
    const int h   = lane >> 5;
    const float ox = (m32 < NCELLS) ? 0.05f * (float)((m32 / 9) - 1)       : 1e4f;
    const float oy = (m32 < NCELLS) ? 0.05f * (float)(((m32 / 3) % 3) - 1) : 1e4f;
    const float oz = (m32 < NCELLS) ? 0.05f * (float)((m32 % 3) - 1)       : 1e4f;

    const char* cb = (const char*)(coefh + (size_t)bi * N_ * C_ + m32);   // + j<<6 bytes

    f32x16 acc;
#pragma unroll
    for (int r = 0; r < 16; ++r) acc[r] = 0.0f;

    const unsigned long long lanemask = (1ull << lane) - 1ull;
    int count = 0;
    float4* myq = candbuf;

    auto flush = [&](int cnt_) {
        // pad queue to a multiple of 16 with far-away sentinels (w -> 0, j -> 0)
        int pad = (16 - (cnt_ & 15)) & 15;
        if (lane < pad) myq[cnt_ + lane] = make_float4(1e4f, 1e4f, 1e4f, __int_as_float(0));
        asm volatile("s_waitcnt lgkmcnt(0)" ::: "memory");
        int nb = (cnt_ + 15) >> 4;
        for (int bt = 0; bt < nb; ++bt) {
            int base = bt * 16 + h * 8;
            float wv[8];
            unsigned cf[8];
#pragma unroll
            for (int b = 0; b < 8; ++b) {
                float4 cd = myq[base + b];        // uniform addr per half-wave -> broadcast
                float tx = cd.x + ox;
                float ty = cd.y + oy;
                float tz = cd.z + oz;
                float d2 = fmaf(tz, tz, fmaf(ty, ty, tx * tx));   // >= 0 always
                float q2 = d2 * 100.0f;
                float q  = __builtin_amdgcn_sqrtf(q2);
                float w1 = fmaf(q2, fmaf(SIG6, q, -SIG6), SIGMA); // sigma*(1-6q^2+6q^3)
                float u1 = 1.0f - q;
                float w2 = (SIG2 * u1) * (u1 * u1);               // <=0 for q>=1
                // w1-w2 = sigma*(2q-1)^3  =>  exact spline = max(min(w1,w2),0)
                wv[b] = fmaxf(fminf(w1, w2), 0.0f);
                cf[b] = *(const unsigned short*)(cb + __float_as_int(cd.w));
            }
            union { bf16x8 v; unsigned u[4]; } aF, bF;
#pragma unroll
            for (int wg = 0; wg < 4; ++wg) {
                unsigned pk;
                asm("v_cvt_pk_bf16_f32 %0, %1, %2" : "=v"(pk)
                    : "v"(wv[2 * wg]), "v"(wv[2 * wg + 1]));
                aF.u[wg] = pk;
                bF.u[wg] = cf[2 * wg] | (cf[2 * wg + 1] << 16);
            }
            acc = __builtin_amdgcn_mfma_f32_32x32x16_bf16(aF.v, bF.v, acc, 0, 0, 0);
        }
    };

    // 9 z-runs of the 3x3x3 bin neighborhood; bounds fetched by lanes 0..8.
    // Per-axis reach is exactly 0.15 (0.05 cell + 0.1 radius):
    //  - z-clip: if query is >= 0.1501 from its bin's lower/upper z-edge, the z-1/z+1
    //    layer cannot contain a hit (az^2 > 0.01002 > RC2TH).
    //  - column prune: min 2D rounded-square distance P to the column's xy-rectangle;
    //    P >= RC2TH  =>  ax^2+ay^2 >= P for every particle in the column => no hit.
    const int qbx = bin1(xi), qby = bin1(yi), qbz = bin1(zi);
    const float zrel_lo = zi - (float)qbz * 0.2f;
    const float zrel_hi = (float)(qbz + 1) * 0.2f - zi;
    const int zlo = (qbz > 0 && zrel_lo < 0.1501f) ? qbz - 1 : qbz;
    const int zhi = (qbz < 4 && zrel_hi < 0.1501f) ? qbz + 1 : qbz;
    int rdx = lane / 3;
    int rdy = lane - rdx * 3;
    int bx = qbx + rdx - 1;
    int by = qby + rdy - 1;
    bool vv = (lane < 9) && (bx >= 0) && (bx < G_) && (by >= 0) && (by < G_);
    // column prune (lanes 0..8): conservative-exact
    float cx0 = (float)bx * 0.2f;
    float cy0 = (float)by * 0.2f;
    float mx = fmaxf(fmaxf(cx0 - xi, xi - (cx0 + 0.2f)), 0.0f);
    float my = fmaxf(fmaxf(cy0 - yi, yi - (cy0 + 0.2f)), 0.0f);
    float px = fmaxf(mx - 0.05f, 0.0f);
    float py = fmaxf(my - 0.05f, 0.0f);
    vv = vv && (fmaf(px, px, py * py) < RC2TH);
    int bb = bi * NBIN + (bx * G_ + by) * G_;
    int vs0 = off[vv ? bb + zlo : 0];
    int vs1 = off[vv ? bb + zhi + 1 : 0];
    // defensive clamp: guarantee bounded loops even under corrupted workspace
    vs0 = vv ? (vs0 < 0 ? 0 : (vs0 > B_ * N_ ? B_ * N_ : vs0)) : 0;
    vs1 = vv ? (vs1 < vs0 ? vs0 : (vs1 > B_ * N_ ? B_ * N_ : vs1)) : 0;

    for (int r = 0; r < 9; ++r) {
        int rs = __shfl(vs0, r);
        int re = __shfl(vs1, r);
        for (int s = rs; s < re; s += 128) {
            int idx0 = s + lane;
            int idx1 = s + 64 + lane;
            bool val0 = idx0 < re;
            bool val1 = idx1 < re;
            float4 pj0 = spos[val0 ? idx0 : rs];   // two independent loads -> MLP 2
            float4 pj1 = spos[val1 ? idx1 : rs];
            // chunk 0 filter
            float dx0 = xi - pj0.x, dy0 = yi - pj0.y, dz0 = zi - pj0.z;
            float ax0 = fmaxf(fabsf(dx0) - 0.05f, 0.0f);
            float ay0 = fmaxf(fabsf(dy0) - 0.05f, 0.0f);
            float az0 = fmaxf(fabsf(dz0) - 0.05f, 0.0f);
            float rc0 = fmaf(az0, az0, fmaf(ay0, ay0, ax0 * ax0));
            bool hit0 = val0 && (rc0 < RC2TH);
            // chunk 1 filter
            float dx1 = xi - pj1.x, dy1 = yi - pj1.y, dz1 = zi - pj1.z;
            float ax1 = fmaxf(fabsf(dx1) - 0.05f, 0.0f);
            float ay1 = fmaxf(fabsf(dy1) - 0.05f, 0.0f);
            float az1 = fmaxf(fabsf(dz1) - 0.05f, 0.0f);
            float rc1 = fmaf(az1, az1, fmaf(ay1, ay1, ax1 * ax1));
            bool hit1 = val1 && (rc1 < RC2TH);
            // compact chunk 0 then chunk 1
            unsigned long long m0 = __ballot(hit0);
            if (hit0) {
                int pos = count + __popcll(m0 & lanemask);
                myq[pos] = make_float4(dx0, dy0, dz0, pj0.w);
            }
            count += __popcll(m0);
            unsigned long long m1 = __ballot(hit1);
            if (hit1) {
                int pos = count + __popcll(m1 & lanemask);
                myq[pos] = make_float4(dx1, dy1, dz1, pj1.w);
            }
            count += __popcll(m1);
            if (count > CAP - 128) { flush(count); count = 0; }
        }
    }
    flush(count);

    // epilogue: f32 acc -> single bf16 plane (row = sorted slot qi)
    // C/D: row m=(r&3)+8*(r>>2)+4*h, col=lane&31
    unsigned short* fh = fieldh + (size_t)qi * FDIM + m32;
#pragma unroll
    for (int r = 0; r < 16; ++r) {
        int m = (r & 3) + 8 * (r >> 2) + 4 * h;
        if (m < NCELLS) fh[m * 32] = bf16_rne(acc[r]);
    }
}

// ---- K3: out = bias + FIELD(8192x864,sorted) . W2(864x32); un-permute rows on store ----
__global__ void __launch_bounds__(64) out_kernel(const unsigned short* __restrict__ fieldh,
                                                 const unsigned short* __restrict__ W2fh,
                                                 const float4* __restrict__ spos,
                                                 const float* __restrict__ bias,
                                                 float* __restrict__ out) {
    const int lane = threadIdx.x;
    const int row0 = blockIdx.x * 16;             // sorted-row tile
    const int arow = row0 + (lane & 15);          // A row (sorted query slot)
    const int kg   = lane >> 4;

    const bf16x8* Bh = reinterpret_cast<const bf16x8*>(W2fh);
    const unsigned short* fh = fieldh + (size_t)arow * FDIM;

    f32x4 acc0, acc1;
#pragma unroll
    for (int r = 0; r < 4; ++r) { acc0[r] = 0.0f; acc1[r] = 0.0f; }

    for (int kc = 0; kc < 27; ++kc) {
        int k0 = kc * 32 + kg * 8;
        bf16x8 ah  = *reinterpret_cast<const bf16x8*>(fh + k0);
        bf16x8 bh0 = Bh[kc * 64 + lane];
        bf16x8 bh1 = Bh[(27 + kc) * 64 + lane];
        acc0 = __builtin_amdgcn_mfma_f32_16x16x32_bf16(ah, bh0, acc0, 0, 0, 0);
        acc1 = __builtin_amdgcn_mfma_f32_16x16x32_bf16(ah, bh1, acc1, 0, 0, 0);
    }

    int col = lane & 15;
    float b0 = bias[col];
    float b1 = bias[16 + col];
#pragma unroll
    for (int r = 0; r < 4; ++r) {
        int srow = row0 + kg * 4 + r;             // sorted slot of this output row
        int oj   = __float_as_int(spos[srow].w) >> 6;          // original index in batch
        int orow = (srow >= N_ ? N_ : 0) + oj;                  // + batch offset
        out[(size_t)orow * O_ + col]      = acc0[r] + b0;
        out[(size_t)orow * O_ + 16 + col] = acc1[r] + b1;
    }
}

extern "C" void kernel_launch(void* const* d_in, const int* in_sizes, int n_in,
                              void* d_out, int out_size, void* d_ws, size_t ws_size,
                              hipStream_t stream) {
    const float* locs    = (const float*)d_in[0];
    const float* data    = (const float*)d_in[1];
    const float* density = (const float*)d_in[2];
    const float* weight  = (const float*)d_in[3];
    const float* bias    = (const float*)d_in[4];
    float* out = (float*)d_out;

    char* base = (char*)d_ws;
    float4* spos           = (float4*)base;                                 // 8192*16B
    unsigned short* fieldh = (unsigned short*)(base + 131072);              // 8192*864 u16
    unsigned short* coefh  = fieldh + (size_t)B_ * N_ * FDIM;               // 262144 u16
    unsigned short* W2fh   = coefh + (size_t)B_ * N_ * C_;                  // 27648 u16
    int* cnt  = (int*)(W2fh + 27648);                                       // 256 ints
    int* wcnt = cnt + 256;                                                  // 256 ints
    int* off  = wcnt + 256;                                                 // 256 ints

    zero_kernel<<<dim3(1), dim3(256), 0, stream>>>(cnt);                    // cnt + wcnt

    // K1: coef 32768 + W2 27648 + histogram 8192 = 68608 = 268*256
    prep_kernel<<<dim3(268), dim3(256), 0, stream>>>(locs, data, density, weight,
                                                     coefh, W2fh, cnt);

    scatter_kernel<<<dim3(32), dim3(256), 0, stream>>>(locs, cnt, wcnt, off, spos);

    // K2: one single-wave block per sorted query
    field_kernel<<<dim3(B_ * N_), dim3(64), 0, stream>>>(spos, off, coefh, fieldh);

    out_kernel<<<dim3((B_ * N_) / 16), dim3(64), 0, stream>>>(fieldh, W2fh, spos,
                                                              bias, out);
}